// Round 8
// baseline (512.191 us; speedup 1.0000x reference)
//
#include <hip/hip_runtime.h>

#define Hc 96
#define Wc 96
#define Cc 256
#define Bc 4
#define KK 9
#define HW 9216          // Hc*Wc
#define PIX 36864        // Bc*HW
#define CK 2304          // Cc*KK

typedef _Float16 f16;
typedef __attribute__((ext_vector_type(4))) _Float16 f16x4;
typedef __attribute__((ext_vector_type(8))) _Float16 f16x8;
typedef __attribute__((ext_vector_type(4))) float f32x4;

__device__ __forceinline__ int clampi(int v, int lo, int hi) {
    return v < lo ? lo : (v > hi ? hi : v);
}

#define SB() __builtin_amdgcn_sched_barrier(0)

// ---------- prep: NCHW fp32 -> NHWC f16 (layer 0 input) ----------
__global__ __launch_bounds__(256) void nhwc_prep_kernel(
    const float* __restrict__ x0, f16* __restrict__ x16)
{
    __shared__ float st[64][65];
    const int hw0 = blockIdx.x * 64;
    const int c0  = blockIdx.y * 64;
    const int b   = blockIdx.z;
    const int tid = threadIdx.x;
    const int a = tid & 63, r = tid >> 6;
#pragma unroll
    for (int it = 0; it < 16; ++it) {
        int cl = it * 4 + r;
        st[cl][a] = x0[((size_t)(b * Cc + c0 + cl)) * HW + hw0 + a];
    }
    __syncthreads();
#pragma unroll
    for (int it = 0; it < 16; ++it) {
        int hwl = it * 4 + r;
        x16[((size_t)(b * HW + hw0 + hwl)) * Cc + c0 + a] = (f16)st[a][hwl];
    }
}

// wT2[(k*256 + o)*256 + c] = (f16) w[(o*256 + c)*9 + k]
__global__ __launch_bounds__(256) void transpose_w_kernel(
    const float* __restrict__ w, f16* __restrict__ wT2)
{
    int u = blockIdx.x * 256 + threadIdx.x;   // < 589824
    int c = u & 255, o = (u >> 8) & 255, k = u >> 16;
    wT2[u] = (f16)w[(o * Cc + c) * KK + k];
}

// woffT[(k*32 + j)*256 + c] = (f16) w_off[(j*256 + c)*9 + k], rows 18..31 = 0
__global__ __launch_bounds__(256) void woff_prep_kernel(
    const float* __restrict__ w_off, f16* __restrict__ woffT)
{
    int u = blockIdx.x * 256 + threadIdx.x;   // < 73728
    int c = u & 255, j = (u >> 8) & 31, k = u >> 13;
    float v = (j < 18) ? w_off[((size_t)j * Cc + c) * KK + k] : 0.f;
    woffT[u] = (f16)v;
}

// bilinear decomposition for one tap -> idx4/wt4 (tap-major layout)
__device__ __forceinline__ void store_tap(int k, int h, int w, float offy, float offx,
    int p, int4* __restrict__ idx4t, float4* __restrict__ wt4t)
{
    float py = (float)(h - 1 + k / 3) + offy;
    float px = (float)(w - 1 + k % 3) + offx;
    float y0f = floorf(py), x0f = floorf(px);
    float wy = py - y0f, wx = px - x0f;
    int iy0 = (int)y0f, ix0 = (int)x0f;
    float vy0 = (y0f >= 0.f && y0f <= 95.f) ? 1.f : 0.f;
    float vy1 = (y0f + 1.f >= 0.f && y0f + 1.f <= 95.f) ? 1.f : 0.f;
    float vx0 = (x0f >= 0.f && x0f <= 95.f) ? 1.f : 0.f;
    float vx1 = (x0f + 1.f >= 0.f && x0f + 1.f <= 95.f) ? 1.f : 0.f;
    int cy0 = clampi(iy0, 0, 95), cy1 = clampi(iy0 + 1, 0, 95);
    int cx0 = clampi(ix0, 0, 95), cx1 = clampi(ix0 + 1, 0, 95);
    idx4t[(size_t)k * PIX + p] = make_int4(cy0 * Wc + cx0, cy0 * Wc + cx1,
                                           cy1 * Wc + cx0, cy1 * Wc + cx1);
    wt4t[(size_t)k * PIX + p] = make_float4((1.f - wy) * (1.f - wx) * vy0 * vx0,
                                            (1.f - wy) * wx * vy0 * vx1,
                                            wy * (1.f - wx) * vy1 * vx0,
                                            wy * wx * vy1 * vx1);
}

// Offset conv as f16 MFMA GEMM, reg-staged double-buffered pipeline.
// Block: 256 threads (4 waves = 2M x 2N), tile 32 out x 64 pixels. 576 blocks.
__global__ __launch_bounds__(256) void conv_off_mfma_kernel(
    const f16* __restrict__ x16, const f16* __restrict__ woffT,
    const float* __restrict__ b_off,
    int4* __restrict__ idx4t, float4* __restrict__ wt4t)
{
    __shared__ __align__(16) f16 s_a[2][32 * 32];   // 2 x 2KB
    __shared__ __align__(16) f16 s_b[2][64 * 32];   // 2 x 4KB
    const int bid = blockIdx.x;
    const int swz = (bid & 7) * 72 + (bid >> 3);    // 576 blocks, XCD-chunked
    const int p0 = swz * 64;
    const int imgb = (p0 / HW) * HW;
    const int tid = threadIdx.x, lane = tid & 63, wid = tid >> 6;
    const int wm = wid >> 1, wn = wid & 1;
    const int qa = ((lane >> 4) ^ ((lane >> 1) & 3)) * 8;
    // A-stage mapping: row/col-quad
    const int arow = tid >> 3, acb = tid & 7;
    const int adst = arow * 32 + (((acb >> 1) ^ ((arow >> 1) & 3)) * 8) + (acb & 1) * 4;
    // B-stage mapping: 4 lanes per pixel (coalesced 64B), pixel ps, group cg
    const int ps = tid >> 2, cg = tid & 3;
    const int bdst = ps * 32 + ((cg ^ ((ps >> 1) & 3)) * 8);
    const int hwp = p0 + ps - imgb;
    const int hp = hwp / Wc, wp = hwp - hp * Wc;

#define CLOAD(q, aD, bD) do {                                                  \
    int p2_ = (q) > 71 ? 71 : (q);                                             \
    int k2_ = p2_ >> 3, c2_ = p2_ & 7;                                         \
    int ky_ = k2_ / 3, kx_ = k2_ - ky_ * 3;                                    \
    int yy_ = hp + ky_ - 1, xx_ = wp + kx_ - 1;                                \
    bool v_ = (yy_ >= 0 && yy_ < Hc && xx_ >= 0 && xx_ < Wc);                  \
    aD = *(const f16x4*)(woffT + ((size_t)(k2_ * 32 + arow)) * Cc + c2_ * 32 + acb * 4); \
    f16x8 t_ = {0, 0, 0, 0, 0, 0, 0, 0};                                       \
    if (v_) t_ = *(const f16x8*)(x16 + ((size_t)(imgb + yy_ * Wc + xx_)) * Cc + c2_ * 32 + cg * 8); \
    bD = t_;                                                                   \
} while (0)

    f32x4 acc[2];
    acc[0] = (f32x4){0.f, 0.f, 0.f, 0.f};
    acc[1] = (f32x4){0.f, 0.f, 0.f, 0.f};

    f16x4 aR0, aR1;
    f16x8 bR0, bR1;
    // prologue: phase 0 -> slot0 -> s[0]; phase 1 -> slot1 (held in regs)
    CLOAD(0, aR0, bR0);
    CLOAD(1, aR1, bR1);
    *(f16x4*)&s_a[0][adst] = aR0;
    *(f16x8*)&s_b[0][bdst] = bR0;
    asm volatile("s_waitcnt lgkmcnt(0)" ::: "memory"); SB();
    __builtin_amdgcn_s_barrier(); SB();

#define CBODY(p, aCur, bCur, aNxt, bNxt, bc, bn) do {                          \
    f16x8 af = *(const f16x8*)&s_a[bc][(wm * 16 + (lane & 15)) * 32 + qa];     \
    f16x8 bf0 = *(const f16x8*)&s_b[bc][(wn * 32 + (lane & 15)) * 32 + qa];    \
    f16x8 bf1 = *(const f16x8*)&s_b[bc][(wn * 32 + 16 + (lane & 15)) * 32 + qa];\
    CLOAD((p) + 2, aCur, bCur);                                                \
    acc[0] = __builtin_amdgcn_mfma_f32_16x16x32_f16(af, bf0, acc[0], 0, 0, 0); \
    acc[1] = __builtin_amdgcn_mfma_f32_16x16x32_f16(af, bf1, acc[1], 0, 0, 0); \
    *(f16x4*)&s_a[bn][adst] = aNxt;                                            \
    *(f16x8*)&s_b[bn][bdst] = bNxt;                                            \
    asm volatile("s_waitcnt lgkmcnt(0)" ::: "memory"); SB();                   \
    __builtin_amdgcn_s_barrier(); SB();                                        \
} while (0)

    for (int p = 0; p < 72; p += 2) {
        CBODY(p,     aR0, bR0, aR1, bR1, 0, 1);
        CBODY(p + 1, aR1, bR1, aR0, bR0, 1, 0);
    }

    // epilogue: wm=0 -> taps 0..7 (rows 4g..4g+3), wm=1 -> tap 8 (rows 16,17)
    const int g = lane >> 4;
#pragma unroll
    for (int ni = 0; ni < 2; ++ni) {
        const int p = p0 + wn * 32 + ni * 16 + (lane & 15);
        const int hwq = p - imgb;
        const int hq = hwq / Wc, wq = hwq - hq * Wc;
        if (wm == 0) {
            store_tap(2 * g,     hq, wq, acc[ni][0] + b_off[4 * g],
                                         acc[ni][1] + b_off[4 * g + 1], p, idx4t, wt4t);
            store_tap(2 * g + 1, hq, wq, acc[ni][2] + b_off[4 * g + 2],
                                         acc[ni][3] + b_off[4 * g + 3], p, idx4t, wt4t);
        } else if (g == 0) {
            store_tap(8, hq, wq, acc[ni][0] + b_off[16],
                                 acc[ni][1] + b_off[17], p, idx4t, wt4t);
        }
    }
#undef CLOAD
#undef CBODY
}

// Fused deformable sampling (f16 NHWC gathers) + f16 MFMA GEMM + ReLU.
// Block: 256 threads (4 waves), tile 256 out x 64 pix; wave = 64x64. 576 blocks.
// Weights (A-fragments) load DIRECT global->register: each lane's fragment is
// contiguous 16B of wT2; no s_w LDS staging at all. LDS holds only samples
// (8KB) -> 3 blocks/CU. Corners prefetched 1 chunk ahead in reg ping-pong.
__global__ __launch_bounds__(256, 3) void deform_mfma_kernel(
    const f16* __restrict__ x16, const f16* __restrict__ wT2,
    const int4* __restrict__ idx4t, const float4* __restrict__ wt4t,
    f16* __restrict__ o16, float* __restrict__ oN, int last)
{
    __shared__ __align__(16) f16 s_s[2][2048];  // 2 x 4KB [pix(64)][kk(32)] swz

    const int bid = blockIdx.x;
    const int swz = (bid & 7) * 72 + (bid >> 3); // 576 blocks, XCD-chunked
    const int p0 = swz * 64;
    const int imgb = (p0 / HW) * HW;
    const int tid = threadIdx.x, lane = tid & 63, wid = tid >> 6;
    const int ps = tid >> 2, cg = tid & 3;       // sampling: pixel ps, 8-ch grp cg
    const int qa = ((lane >> 4) ^ ((lane >> 1) & 3)) * 8;
    const int qs = (cg ^ ((ps >> 1) & 3)) * 8;
    const f16* xb = x16 + (size_t)imgb * Cc;
    // per-lane weight base: row (wid*64 + lane&15), chan (lane>>4)*8
    const f16* wbase = wT2 + ((size_t)(wid * 64 + (lane & 15))) * Cc + (lane >> 4) * 8;

// A-fragments for (tap kt, chunk cw): 4 x contiguous 16B per lane
#define ISSUE_AF(dst, kt, cw) do {                                             \
    _Pragma("unroll")                                                          \
    for (int mi_ = 0; mi_ < 4; ++mi_)                                          \
        (dst)[mi_] = *(const f16x8*)(wbase + ((size_t)((kt) * 256 + mi_ * 16)) * Cc + (cw) * 32); \
} while (0)

// 4 lanes (cg=0..3) of pixel ps read contiguous 64B per corner
#define ISSUE_C(dst, idv, co) do {                                             \
    (dst)[0] = *(const f16x8*)(xb + (size_t)(idv).x * Cc + (co) + cg * 8);     \
    (dst)[1] = *(const f16x8*)(xb + (size_t)(idv).y * Cc + (co) + cg * 8);     \
    (dst)[2] = *(const f16x8*)(xb + (size_t)(idv).z * Cc + (co) + cg * 8);     \
    (dst)[3] = *(const f16x8*)(xb + (size_t)(idv).w * Cc + (co) + cg * 8);     \
} while (0)

#define BLEND_WRITE(src, wvv, nb) do {                                         \
    f16x8 sv_;                                                                 \
    _Pragma("unroll")                                                          \
    for (int j_ = 0; j_ < 8; ++j_) {                                           \
        float s_ = (wvv).x * (float)(src)[0][j_] + (wvv).y * (float)(src)[1][j_]\
                 + (wvv).z * (float)(src)[2][j_] + (wvv).w * (float)(src)[3][j_];\
        sv_[j_] = (f16)s_;                                                     \
    }                                                                          \
    *(f16x8*)&s_s[nb][ps * 32 + qs] = sv_;                                     \
} while (0)

    f32x4 acc[4][4];
#pragma unroll
    for (int mi = 0; mi < 4; ++mi)
#pragma unroll
        for (int ni = 0; ni < 4; ++ni) acc[mi][ni] = (f32x4){0.f, 0.f, 0.f, 0.f};

    f16x8 c4[2][4];
    int4 id = idx4t[p0 + ps];
    float4 wv = wt4t[p0 + ps];
    int4 idN;
    float4 wvN;

    // prologue: C(chunk0)->blend->s_s[0]; C(chunk1) left in flight
    ISSUE_C(c4[1], id, 0);                 // corners for chunk 0
    ISSUE_C(c4[0], id, 32);                // corners for chunk 1
    BLEND_WRITE(c4[1], wv, 0);             // counted vmcnt waits c4[1] only
    asm volatile("s_waitcnt lgkmcnt(0)" ::: "memory"); SB();
    __builtin_amdgcn_s_barrier(); SB();

    for (int k = 0; k < 9; ++k) {
        const int kn = (k < 8) ? k + 1 : 8;
#pragma unroll
        for (int ch = 0; ch < 8; ++ch) {
            const int bb = ch & 1, nb = bb ^ 1;
            f16x8 af[4], bf[4];
            // weights for THIS chunk: direct global->reg, issued first so the
            // in-flight corners + blend cover most of their L2 latency
            ISSUE_AF(af, k, ch);
            SB();
#pragma unroll
            for (int ni = 0; ni < 4; ++ni)
                bf[ni] = *(const f16x8*)&s_s[bb][(ni * 16 + (lane & 15)) * 32 + qa];
            if (ch == 0) {
                idN = idx4t[(size_t)kn * PIX + p0 + ps];
                wvN = wt4t[(size_t)kn * PIX + p0 + ps];
            }
            // corners for chunk t+2
            {
                const int4 idu = (ch >= 6) ? idN : id;
                ISSUE_C(c4[nb], idu, ((ch + 2) & 7) * 32);
            }
            // blend corners for chunk t+1 (issued last chunk; counted vmcnt)
            {
                const float4 wvu = (ch == 7) ? wvN : wv;
                BLEND_WRITE(c4[bb], wvu, nb);
            }
            asm volatile("s_waitcnt lgkmcnt(0)" ::: "memory"); SB();
#pragma unroll
            for (int ni = 0; ni < 4; ++ni)
#pragma unroll
                for (int mi = 0; mi < 4; ++mi)
                    acc[mi][ni] = __builtin_amdgcn_mfma_f32_16x16x32_f16(
                        af[mi], bf[ni], acc[mi][ni], 0, 0, 0);
            __builtin_amdgcn_s_barrier(); SB();
        }
        id = idN;
        wv = wvN;
    }

    // epilogue: ReLU; D row = output = (lane>>4)*4+j, col = pixel = lane&15
    if (!last) {
#pragma unroll
        for (int ni = 0; ni < 4; ++ni) {
            const int p = p0 + ni * 16 + (lane & 15);
#pragma unroll
            for (int mi = 0; mi < 4; ++mi) {
                const int o0 = wid * 64 + mi * 16 + (lane >> 4) * 4;
                f32x4 v = acc[mi][ni];
                f16x4 h = {(f16)fmaxf(v[0], 0.f), (f16)fmaxf(v[1], 0.f),
                           (f16)fmaxf(v[2], 0.f), (f16)fmaxf(v[3], 0.f)};
                *(f16x4*)&o16[(size_t)p * Cc + o0] = h;
            }
        }
    } else {
        const int bimg = imgb / HW;
#pragma unroll
        for (int ni = 0; ni < 4; ++ni) {
            const int p = p0 + ni * 16 + (lane & 15);
            const int hwl = p - imgb;
#pragma unroll
            for (int mi = 0; mi < 4; ++mi) {
                const int o0 = wid * 64 + mi * 16 + (lane >> 4) * 4;
#pragma unroll
                for (int j = 0; j < 4; ++j)
                    oN[((size_t)(bimg * Cc + o0 + j)) * HW + hwl] =
                        fmaxf(acc[mi][ni][j], 0.f);
            }
        }
    }
#undef ISSUE_AF
#undef ISSUE_C
#undef BLEND_WRITE
}

extern "C" void kernel_launch(void* const* d_in, const int* in_sizes, int n_in,
                              void* d_out, int out_size, void* d_ws, size_t ws_size,
                              hipStream_t stream)
{
    const float* x0 = (const float*)d_in[0];
    float* out = (float*)d_out;

    f16*   x16a = (f16*)d_ws;                          // PIX*Cc f16
    f16*   x16b = x16a + (size_t)PIX * Cc;             // PIX*Cc f16
    f16*   wT2  = x16b + (size_t)PIX * Cc;             // CK*Cc f16
    f16*   woffT = wT2 + (size_t)CK * Cc;              // 9*32*256 f16
    int4*  idx4t = (int4*)(woffT + (size_t)9 * 32 * Cc);
    float4* wt4t = (float4*)(idx4t + (size_t)KK * PIX);

    nhwc_prep_kernel<<<dim3(HW / 64, Cc / 64, Bc), 256, 0, stream>>>(x0, x16a);

    const f16* xin = x16a;
    for (int L = 0; L < 3; ++L) {
        const float* w_off = (const float*)d_in[1 + 3 * L];
        const float* b_off = (const float*)d_in[2 + 3 * L];
        const float* w     = (const float*)d_in[3 + 3 * L];
        const int last = (L == 2);
        f16* xo = (L == 0) ? x16b : x16a;

        transpose_w_kernel<<<(CK * Cc) / 256, 256, 0, stream>>>(w, wT2);
        woff_prep_kernel<<<(9 * 32 * Cc) / 256, 256, 0, stream>>>(w_off, woffT);
        conv_off_mfma_kernel<<<PIX / 64, 256, 0, stream>>>(xin, woffT, b_off, idx4t, wt4t);
        deform_mfma_kernel<<<PIX / 64, 256, 0, stream>>>(
            xin, wT2, idx4t, wt4t, xo, out, last);

        xin = xo;
    }
}

// Round 9
// 498.572 us; speedup vs baseline: 1.0273x; 1.0273x over previous
//
#include <hip/hip_runtime.h>

#define Hc 96
#define Wc 96
#define Cc 256
#define Bc 4
#define KK 9
#define HW 9216          // Hc*Wc
#define PIX 36864        // Bc*HW
#define CK 2304          // Cc*KK

typedef _Float16 f16;
typedef __attribute__((ext_vector_type(4))) _Float16 f16x4;
typedef __attribute__((ext_vector_type(8))) _Float16 f16x8;
typedef __attribute__((ext_vector_type(4))) float f32x4;

__device__ __forceinline__ int clampi(int v, int lo, int hi) {
    return v < lo ? lo : (v > hi ? hi : v);
}

#define SB() __builtin_amdgcn_sched_barrier(0)

// ---------- prep: NCHW fp32 -> NHWC f16 (layer 0 input) ----------
__global__ __launch_bounds__(256) void nhwc_prep_kernel(
    const float* __restrict__ x0, f16* __restrict__ x16)
{
    __shared__ float st[64][65];
    const int hw0 = blockIdx.x * 64;
    const int c0  = blockIdx.y * 64;
    const int b   = blockIdx.z;
    const int tid = threadIdx.x;
    const int a = tid & 63, r = tid >> 6;
#pragma unroll
    for (int it = 0; it < 16; ++it) {
        int cl = it * 4 + r;
        st[cl][a] = x0[((size_t)(b * Cc + c0 + cl)) * HW + hw0 + a];
    }
    __syncthreads();
#pragma unroll
    for (int it = 0; it < 16; ++it) {
        int hwl = it * 4 + r;
        x16[((size_t)(b * HW + hw0 + hwl)) * Cc + c0 + a] = (f16)st[a][hwl];
    }
}

// wT2[(k*256 + o)*256 + c] = (f16) w[(o*256 + c)*9 + k]
__global__ __launch_bounds__(256) void transpose_w_kernel(
    const float* __restrict__ w, f16* __restrict__ wT2)
{
    int u = blockIdx.x * 256 + threadIdx.x;   // < 589824
    int c = u & 255, o = (u >> 8) & 255, k = u >> 16;
    wT2[u] = (f16)w[(o * Cc + c) * KK + k];
}

// woffT[(k*32 + j)*256 + c] = (f16) w_off[(j*256 + c)*9 + k], rows 18..31 = 0
__global__ __launch_bounds__(256) void woff_prep_kernel(
    const float* __restrict__ w_off, f16* __restrict__ woffT)
{
    int u = blockIdx.x * 256 + threadIdx.x;   // < 73728
    int c = u & 255, j = (u >> 8) & 31, k = u >> 13;
    float v = (j < 18) ? w_off[((size_t)j * Cc + c) * KK + k] : 0.f;
    woffT[u] = (f16)v;
}

// bilinear decomposition for one tap -> idx4/wt4 (tap-major layout)
__device__ __forceinline__ void store_tap(int k, int h, int w, float offy, float offx,
    int p, int4* __restrict__ idx4t, float4* __restrict__ wt4t)
{
    float py = (float)(h - 1 + k / 3) + offy;
    float px = (float)(w - 1 + k % 3) + offx;
    float y0f = floorf(py), x0f = floorf(px);
    float wy = py - y0f, wx = px - x0f;
    int iy0 = (int)y0f, ix0 = (int)x0f;
    float vy0 = (y0f >= 0.f && y0f <= 95.f) ? 1.f : 0.f;
    float vy1 = (y0f + 1.f >= 0.f && y0f + 1.f <= 95.f) ? 1.f : 0.f;
    float vx0 = (x0f >= 0.f && x0f <= 95.f) ? 1.f : 0.f;
    float vx1 = (x0f + 1.f >= 0.f && x0f + 1.f <= 95.f) ? 1.f : 0.f;
    int cy0 = clampi(iy0, 0, 95), cy1 = clampi(iy0 + 1, 0, 95);
    int cx0 = clampi(ix0, 0, 95), cx1 = clampi(ix0 + 1, 0, 95);
    idx4t[(size_t)k * PIX + p] = make_int4(cy0 * Wc + cx0, cy0 * Wc + cx1,
                                           cy1 * Wc + cx0, cy1 * Wc + cx1);
    wt4t[(size_t)k * PIX + p] = make_float4((1.f - wy) * (1.f - wx) * vy0 * vx0,
                                            (1.f - wy) * wx * vy0 * vx1,
                                            wy * (1.f - wx) * vy1 * vx0,
                                            wy * wx * vy1 * vx1);
}

// Offset conv as f16 MFMA GEMM, reg-staged double-buffered pipeline.
// Block: 256 threads (4 waves = 2M x 2N), tile 32 out x 64 pixels. 576 blocks.
__global__ __launch_bounds__(256) void conv_off_mfma_kernel(
    const f16* __restrict__ x16, const f16* __restrict__ woffT,
    const float* __restrict__ b_off,
    int4* __restrict__ idx4t, float4* __restrict__ wt4t)
{
    __shared__ __align__(16) f16 s_a[2][32 * 32];   // 2 x 2KB
    __shared__ __align__(16) f16 s_b[2][64 * 32];   // 2 x 4KB
    const int bid = blockIdx.x;
    const int swz = (bid & 7) * 72 + (bid >> 3);    // 576 blocks, XCD-chunked
    const int p0 = swz * 64;
    const int imgb = (p0 / HW) * HW;
    const int tid = threadIdx.x, lane = tid & 63, wid = tid >> 6;
    const int wm = wid >> 1, wn = wid & 1;
    const int qa = ((lane >> 4) ^ ((lane >> 1) & 3)) * 8;
    // A-stage mapping: row/col-quad
    const int arow = tid >> 3, acb = tid & 7;
    const int adst = arow * 32 + (((acb >> 1) ^ ((arow >> 1) & 3)) * 8) + (acb & 1) * 4;
    // B-stage mapping: 4 lanes per pixel (coalesced 64B), pixel ps, group cg
    const int ps = tid >> 2, cg = tid & 3;
    const int bdst = ps * 32 + ((cg ^ ((ps >> 1) & 3)) * 8);
    const int hwp = p0 + ps - imgb;
    const int hp = hwp / Wc, wp = hwp - hp * Wc;

#define CLOAD(q, aD, bD) do {                                                  \
    int p2_ = (q) > 71 ? 71 : (q);                                             \
    int k2_ = p2_ >> 3, c2_ = p2_ & 7;                                         \
    int ky_ = k2_ / 3, kx_ = k2_ - ky_ * 3;                                    \
    int yy_ = hp + ky_ - 1, xx_ = wp + kx_ - 1;                                \
    bool v_ = (yy_ >= 0 && yy_ < Hc && xx_ >= 0 && xx_ < Wc);                  \
    aD = *(const f16x4*)(woffT + ((size_t)(k2_ * 32 + arow)) * Cc + c2_ * 32 + acb * 4); \
    f16x8 t_ = {0, 0, 0, 0, 0, 0, 0, 0};                                       \
    if (v_) t_ = *(const f16x8*)(x16 + ((size_t)(imgb + yy_ * Wc + xx_)) * Cc + c2_ * 32 + cg * 8); \
    bD = t_;                                                                   \
} while (0)

    f32x4 acc[2];
    acc[0] = (f32x4){0.f, 0.f, 0.f, 0.f};
    acc[1] = (f32x4){0.f, 0.f, 0.f, 0.f};

    f16x4 aR0, aR1;
    f16x8 bR0, bR1;
    // prologue: phase 0 -> slot0 -> s[0]; phase 1 -> slot1 (held in regs)
    CLOAD(0, aR0, bR0);
    CLOAD(1, aR1, bR1);
    *(f16x4*)&s_a[0][adst] = aR0;
    *(f16x8*)&s_b[0][bdst] = bR0;
    asm volatile("s_waitcnt lgkmcnt(0)" ::: "memory"); SB();
    __builtin_amdgcn_s_barrier(); SB();

#define CBODY(p, aCur, bCur, aNxt, bNxt, bc, bn) do {                          \
    f16x8 af = *(const f16x8*)&s_a[bc][(wm * 16 + (lane & 15)) * 32 + qa];     \
    f16x8 bf0 = *(const f16x8*)&s_b[bc][(wn * 32 + (lane & 15)) * 32 + qa];    \
    f16x8 bf1 = *(const f16x8*)&s_b[bc][(wn * 32 + 16 + (lane & 15)) * 32 + qa];\
    CLOAD((p) + 2, aCur, bCur);                                                \
    acc[0] = __builtin_amdgcn_mfma_f32_16x16x32_f16(af, bf0, acc[0], 0, 0, 0); \
    acc[1] = __builtin_amdgcn_mfma_f32_16x16x32_f16(af, bf1, acc[1], 0, 0, 0); \
    *(f16x4*)&s_a[bn][adst] = aNxt;                                            \
    *(f16x8*)&s_b[bn][bdst] = bNxt;                                            \
    asm volatile("s_waitcnt lgkmcnt(0)" ::: "memory"); SB();                   \
    __builtin_amdgcn_s_barrier(); SB();                                        \
} while (0)

    for (int p = 0; p < 72; p += 2) {
        CBODY(p,     aR0, bR0, aR1, bR1, 0, 1);
        CBODY(p + 1, aR1, bR1, aR0, bR0, 1, 0);
    }

    // epilogue: wm=0 -> taps 0..7 (rows 4g..4g+3), wm=1 -> tap 8 (rows 16,17)
    const int g = lane >> 4;
#pragma unroll
    for (int ni = 0; ni < 2; ++ni) {
        const int p = p0 + wn * 32 + ni * 16 + (lane & 15);
        const int hwq = p - imgb;
        const int hq = hwq / Wc, wq = hwq - hq * Wc;
        if (wm == 0) {
            store_tap(2 * g,     hq, wq, acc[ni][0] + b_off[4 * g],
                                         acc[ni][1] + b_off[4 * g + 1], p, idx4t, wt4t);
            store_tap(2 * g + 1, hq, wq, acc[ni][2] + b_off[4 * g + 2],
                                         acc[ni][3] + b_off[4 * g + 3], p, idx4t, wt4t);
        } else if (g == 0) {
            store_tap(8, hq, wq, acc[ni][0] + b_off[16],
                                 acc[ni][1] + b_off[17], p, idx4t, wt4t);
        }
    }
#undef CLOAD
#undef CBODY
}

// Fused deformable sampling (f16 NHWC gathers) + f16 MFMA GEMM + ReLU.
// Block: 256 threads (4 waves), tile 128 out x 64 pix; wave = 32x64.
// 1152 blocks = 576 pixel-tiles x 2 M-halves (sibling blocks share an XCD
// -> corner/idx reads are L2-local). LDS 40KB -> 4 blocks/CU resident.
// Weights 2 chunks ahead into 4-deep 8KB ring; readiness via in-order vmcnt
// (W issued before C at t-2, blend at t-1 waits C => W retired). R7-proven.
__global__ __launch_bounds__(256, 4) void deform_mfma_kernel(
    const f16* __restrict__ x16, const f16* __restrict__ wT2,
    const int4* __restrict__ idx4t, const float4* __restrict__ wt4t,
    f16* __restrict__ o16, float* __restrict__ oN, int last)
{
    __shared__ __align__(16) f16 s_w[4][4096];  // 4 x 8KB ring [o(128)][kk(32)] swz
    __shared__ __align__(16) f16 s_s[2][2048];  // 2 x 4KB [pix(64)][kk(32)] swz

    const int bid = blockIdx.x;
    const int swz = (bid & 7) * 144 + (bid >> 3); // 1152 blocks, XCD-chunked
    const int p0 = (swz >> 1) * 64;
    const int ob = (swz & 1) * 128;               // M-half
    const int imgb = (p0 / HW) * HW;
    const int tid = threadIdx.x, lane = tid & 63, wid = tid >> 6;
    const int ps = tid >> 2, cg = tid & 3;       // sampling: pixel ps, 8-ch grp cg
    const int qa = ((lane >> 4) ^ ((lane >> 1) & 3)) * 8;
    const int qs = (cg ^ ((ps >> 1) & 3)) * 8;
    const f16* xb = x16 + (size_t)imgb * Cc;

#define ISSUE_W(kt, cw, nb) do {                                               \
    _Pragma("unroll")                                                          \
    for (int i_ = 0; i_ < 2; ++i_) {                                           \
        int u_ = i_ * 256 + tid;                                               \
        int wr_ = u_ >> 2;                                                     \
        int wc_ = ((u_ & 3) ^ ((u_ >> 3) & 3)) * 8;                            \
        const f16* g_ = wT2 + ((size_t)((kt) * 256 + ob + wr_)) * Cc + (cw) * 32 + wc_; \
        __builtin_amdgcn_global_load_lds(                                      \
            (const __attribute__((address_space(1))) void*)g_,                 \
            (__attribute__((address_space(3))) void*)&s_w[nb][u_ * 8], 16, 0, 0); \
    }                                                                          \
} while (0)

// 4 lanes (cg=0..3) of pixel ps read contiguous 64B per corner
#define ISSUE_C(dst, idv, co) do {                                             \
    (dst)[0] = *(const f16x8*)(xb + (size_t)(idv).x * Cc + (co) + cg * 8);     \
    (dst)[1] = *(const f16x8*)(xb + (size_t)(idv).y * Cc + (co) + cg * 8);     \
    (dst)[2] = *(const f16x8*)(xb + (size_t)(idv).z * Cc + (co) + cg * 8);     \
    (dst)[3] = *(const f16x8*)(xb + (size_t)(idv).w * Cc + (co) + cg * 8);     \
} while (0)

#define BLEND_WRITE(src, wvv, nb) do {                                         \
    f16x8 sv_;                                                                 \
    _Pragma("unroll")                                                          \
    for (int j_ = 0; j_ < 8; ++j_) {                                           \
        float s_ = (wvv).x * (float)(src)[0][j_] + (wvv).y * (float)(src)[1][j_]\
                 + (wvv).z * (float)(src)[2][j_] + (wvv).w * (float)(src)[3][j_];\
        sv_[j_] = (f16)s_;                                                     \
    }                                                                          \
    *(f16x8*)&s_s[nb][ps * 32 + qs] = sv_;                                     \
} while (0)

    f32x4 acc[2][4];
#pragma unroll
    for (int mi = 0; mi < 2; ++mi)
#pragma unroll
        for (int ni = 0; ni < 4; ++ni) acc[mi][ni] = (f32x4){0.f, 0.f, 0.f, 0.f};

    f16x8 c4[2][4];
    int4 id = idx4t[p0 + ps];
    float4 wv = wt4t[p0 + ps];
    int4 idN;
    float4 wvN;

    // prologue: W(t=0)->ring0, W(t=1)->ring1; C(chunk0)->blend->s_s[0];
    // C(chunk1) left in flight (blended at chunk 0).
    ISSUE_W(0, 0, 0);
    ISSUE_W(0, 1, 1);
    SB();
    ISSUE_C(c4[1], id, 0);                 // corners for chunk 0
    ISSUE_C(c4[0], id, 32);                // corners for chunk 1
    BLEND_WRITE(c4[1], wv, 0);             // compiler waits W0,W1,C0 (in-order)
    asm volatile("s_waitcnt lgkmcnt(0)" ::: "memory"); SB();
    __builtin_amdgcn_s_barrier(); SB();

    for (int k = 0; k < 9; ++k) {
        const int kn = (k < 8) ? k + 1 : 8;
#pragma unroll
        for (int ch = 0; ch < 8; ++ch) {
            const int bb = ch & 1, nb = bb ^ 1;
            const int wb = ch & 3, wnb = (ch + 2) & 3;
            f16x8 af[2], bf[4];
#pragma unroll
            for (int mi = 0; mi < 2; ++mi)
                af[mi] = *(const f16x8*)&s_w[wb][(wid * 32 + mi * 16 + (lane & 15)) * 32 + qa];
#pragma unroll
            for (int ni = 0; ni < 4; ++ni)
                bf[ni] = *(const f16x8*)&s_s[bb][(ni * 16 + (lane & 15)) * 32 + qa];
            if (ch == 0) {
                idN = idx4t[(size_t)kn * PIX + p0 + ps];
                wvN = wt4t[(size_t)kn * PIX + p0 + ps];
            }
            // weights two chunks ahead (ring), then corners (order pinned by SB)
            ISSUE_W((ch >= 6) ? kn : k, (ch + 2) & 7, wnb);
            SB();
            {
                const int4 idu = (ch >= 6) ? idN : id;
                ISSUE_C(c4[nb], idu, ((ch + 2) & 7) * 32);
            }
            // blend corners for chunk t+1 (issued last chunk; compiler's
            // counted vmcnt here also retires W(t+1) -> ring buffer ready)
            {
                const float4 wvu = (ch == 7) ? wvN : wv;
                BLEND_WRITE(c4[bb], wvu, nb);
            }
            asm volatile("s_waitcnt lgkmcnt(0)" ::: "memory"); SB();
#pragma unroll
            for (int ni = 0; ni < 4; ++ni)
#pragma unroll
                for (int mi = 0; mi < 2; ++mi)
                    acc[mi][ni] = __builtin_amdgcn_mfma_f32_16x16x32_f16(
                        af[mi], bf[ni], acc[mi][ni], 0, 0, 0);
            __builtin_amdgcn_s_barrier(); SB();
        }
        id = idN;
        wv = wvN;
    }

    // epilogue: ReLU; D row = output = (lane>>4)*4+j, col = pixel = lane&15
    if (!last) {
#pragma unroll
        for (int ni = 0; ni < 4; ++ni) {
            const int p = p0 + ni * 16 + (lane & 15);
#pragma unroll
            for (int mi = 0; mi < 2; ++mi) {
                const int o0 = ob + wid * 32 + mi * 16 + (lane >> 4) * 4;
                f32x4 v = acc[mi][ni];
                f16x4 h = {(f16)fmaxf(v[0], 0.f), (f16)fmaxf(v[1], 0.f),
                           (f16)fmaxf(v[2], 0.f), (f16)fmaxf(v[3], 0.f)};
                *(f16x4*)&o16[(size_t)p * Cc + o0] = h;
            }
        }
    } else {
        const int bimg = imgb / HW;
#pragma unroll
        for (int ni = 0; ni < 4; ++ni) {
            const int p = p0 + ni * 16 + (lane & 15);
            const int hwl = p - imgb;
#pragma unroll
            for (int mi = 0; mi < 2; ++mi) {
                const int o0 = ob + wid * 32 + mi * 16 + (lane >> 4) * 4;
#pragma unroll
                for (int j = 0; j < 4; ++j)
                    oN[((size_t)(bimg * Cc + o0 + j)) * HW + hwl] =
                        fmaxf(acc[mi][ni][j], 0.f);
            }
        }
    }
#undef ISSUE_W
#undef ISSUE_C
#undef BLEND_WRITE
}

extern "C" void kernel_launch(void* const* d_in, const int* in_sizes, int n_in,
                              void* d_out, int out_size, void* d_ws, size_t ws_size,
                              hipStream_t stream)
{
    const float* x0 = (const float*)d_in[0];
    float* out = (float*)d_out;

    f16*   x16a = (f16*)d_ws;                          // PIX*Cc f16
    f16*   x16b = x16a + (size_t)PIX * Cc;             // PIX*Cc f16
    f16*   wT2  = x16b + (size_t)PIX * Cc;             // CK*Cc f16
    f16*   woffT = wT2 + (size_t)CK * Cc;              // 9*32*256 f16
    int4*  idx4t = (int4*)(woffT + (size_t)9 * 32 * Cc);
    float4* wt4t = (float4*)(idx4t + (size_t)KK * PIX);

    nhwc_prep_kernel<<<dim3(HW / 64, Cc / 64, Bc), 256, 0, stream>>>(x0, x16a);

    const f16* xin = x16a;
    for (int L = 0; L < 3; ++L) {
        const float* w_off = (const float*)d_in[1 + 3 * L];
        const float* b_off = (const float*)d_in[2 + 3 * L];
        const float* w     = (const float*)d_in[3 + 3 * L];
        const int last = (L == 2);
        f16* xo = (L == 0) ? x16b : x16a;

        transpose_w_kernel<<<(CK * Cc) / 256, 256, 0, stream>>>(w, wT2);
        woff_prep_kernel<<<(9 * 32 * Cc) / 256, 256, 0, stream>>>(w_off, woffT);
        conv_off_mfma_kernel<<<PIX / 64, 256, 0, stream>>>(xin, woffT, b_off, idx4t, wt4t);
        deform_mfma_kernel<<<PIX / 64 * 2, 256, 0, stream>>>(
            xin, wT2, idx4t, wt4t, xo, out, last);

        xin = xo;
    }
}

// Round 10
// 497.140 us; speedup vs baseline: 1.0303x; 1.0029x over previous
//
#include <hip/hip_runtime.h>

#define Hc 96
#define Wc 96
#define Cc 256
#define Bc 4
#define KK 9
#define HW 9216          // Hc*Wc
#define PIX 36864        // Bc*HW
#define CK 2304          // Cc*KK

typedef _Float16 f16;
typedef __attribute__((ext_vector_type(4))) _Float16 f16x4;
typedef __attribute__((ext_vector_type(8))) _Float16 f16x8;
typedef __attribute__((ext_vector_type(4))) float f32x4;

__device__ __forceinline__ int clampi(int v, int lo, int hi) {
    return v < lo ? lo : (v > hi ? hi : v);
}

#define SB() __builtin_amdgcn_sched_barrier(0)

// ---------- prep: NCHW fp32 -> NHWC f16 (layer 0 input) ----------
__global__ __launch_bounds__(256) void nhwc_prep_kernel(
    const float* __restrict__ x0, f16* __restrict__ x16)
{
    __shared__ float st[64][65];
    const int hw0 = blockIdx.x * 64;
    const int c0  = blockIdx.y * 64;
    const int b   = blockIdx.z;
    const int tid = threadIdx.x;
    const int a = tid & 63, r = tid >> 6;
#pragma unroll
    for (int it = 0; it < 16; ++it) {
        int cl = it * 4 + r;
        st[cl][a] = x0[((size_t)(b * Cc + c0 + cl)) * HW + hw0 + a];
    }
    __syncthreads();
#pragma unroll
    for (int it = 0; it < 16; ++it) {
        int hwl = it * 4 + r;
        x16[((size_t)(b * HW + hw0 + hwl)) * Cc + c0 + a] = (f16)st[a][hwl];
    }
}

// wT2[(k*256 + o)*256 + c] = (f16) w[(o*256 + c)*9 + k]
__global__ __launch_bounds__(256) void transpose_w_kernel(
    const float* __restrict__ w, f16* __restrict__ wT2)
{
    int u = blockIdx.x * 256 + threadIdx.x;   // < 589824
    int c = u & 255, o = (u >> 8) & 255, k = u >> 16;
    wT2[u] = (f16)w[(o * Cc + c) * KK + k];
}

// woffT[(k*32 + j)*256 + c] = (f16) w_off[(j*256 + c)*9 + k], rows 18..31 = 0
__global__ __launch_bounds__(256) void woff_prep_kernel(
    const float* __restrict__ w_off, f16* __restrict__ woffT)
{
    int u = blockIdx.x * 256 + threadIdx.x;   // < 73728
    int c = u & 255, j = (u >> 8) & 31, k = u >> 13;
    float v = (j < 18) ? w_off[((size_t)j * Cc + c) * KK + k] : 0.f;
    woffT[u] = (f16)v;
}

// bilinear decomposition for one tap -> idx4/wt4 (tap-major layout)
__device__ __forceinline__ void store_tap(int k, int h, int w, float offy, float offx,
    int p, int4* __restrict__ idx4t, float4* __restrict__ wt4t)
{
    float py = (float)(h - 1 + k / 3) + offy;
    float px = (float)(w - 1 + k % 3) + offx;
    float y0f = floorf(py), x0f = floorf(px);
    float wy = py - y0f, wx = px - x0f;
    int iy0 = (int)y0f, ix0 = (int)x0f;
    float vy0 = (y0f >= 0.f && y0f <= 95.f) ? 1.f : 0.f;
    float vy1 = (y0f + 1.f >= 0.f && y0f + 1.f <= 95.f) ? 1.f : 0.f;
    float vx0 = (x0f >= 0.f && x0f <= 95.f) ? 1.f : 0.f;
    float vx1 = (x0f + 1.f >= 0.f && x0f + 1.f <= 95.f) ? 1.f : 0.f;
    int cy0 = clampi(iy0, 0, 95), cy1 = clampi(iy0 + 1, 0, 95);
    int cx0 = clampi(ix0, 0, 95), cx1 = clampi(ix0 + 1, 0, 95);
    idx4t[(size_t)k * PIX + p] = make_int4(cy0 * Wc + cx0, cy0 * Wc + cx1,
                                           cy1 * Wc + cx0, cy1 * Wc + cx1);
    wt4t[(size_t)k * PIX + p] = make_float4((1.f - wy) * (1.f - wx) * vy0 * vx0,
                                            (1.f - wy) * wx * vy0 * vx1,
                                            wy * (1.f - wx) * vy1 * vx0,
                                            wy * wx * vy1 * vx1);
}

// Offset conv as f16 MFMA GEMM, reg-staged double-buffered pipeline.
// Block: 256 threads (4 waves = 2M x 2N), tile 32 out x 64 pixels. 576 blocks.
__global__ __launch_bounds__(256) void conv_off_mfma_kernel(
    const f16* __restrict__ x16, const f16* __restrict__ woffT,
    const float* __restrict__ b_off,
    int4* __restrict__ idx4t, float4* __restrict__ wt4t)
{
    __shared__ __align__(16) f16 s_a[2][32 * 32];   // 2 x 2KB
    __shared__ __align__(16) f16 s_b[2][64 * 32];   // 2 x 4KB
    const int bid = blockIdx.x;
    const int swz = (bid & 7) * 72 + (bid >> 3);    // 576 blocks, XCD-chunked
    const int p0 = swz * 64;
    const int imgb = (p0 / HW) * HW;
    const int tid = threadIdx.x, lane = tid & 63, wid = tid >> 6;
    const int wm = wid >> 1, wn = wid & 1;
    const int qa = ((lane >> 4) ^ ((lane >> 1) & 3)) * 8;
    // A-stage mapping: row/col-quad
    const int arow = tid >> 3, acb = tid & 7;
    const int adst = arow * 32 + (((acb >> 1) ^ ((arow >> 1) & 3)) * 8) + (acb & 1) * 4;
    // B-stage mapping: 4 lanes per pixel (coalesced 64B), pixel ps, group cg
    const int ps = tid >> 2, cg = tid & 3;
    const int bdst = ps * 32 + ((cg ^ ((ps >> 1) & 3)) * 8);
    const int hwp = p0 + ps - imgb;
    const int hp = hwp / Wc, wp = hwp - hp * Wc;

#define CLOAD(q, aD, bD) do {                                                  \
    int p2_ = (q) > 71 ? 71 : (q);                                             \
    int k2_ = p2_ >> 3, c2_ = p2_ & 7;                                         \
    int ky_ = k2_ / 3, kx_ = k2_ - ky_ * 3;                                    \
    int yy_ = hp + ky_ - 1, xx_ = wp + kx_ - 1;                                \
    bool v_ = (yy_ >= 0 && yy_ < Hc && xx_ >= 0 && xx_ < Wc);                  \
    aD = *(const f16x4*)(woffT + ((size_t)(k2_ * 32 + arow)) * Cc + c2_ * 32 + acb * 4); \
    f16x8 t_ = {0, 0, 0, 0, 0, 0, 0, 0};                                       \
    if (v_) t_ = *(const f16x8*)(x16 + ((size_t)(imgb + yy_ * Wc + xx_)) * Cc + c2_ * 32 + cg * 8); \
    bD = t_;                                                                   \
} while (0)

    f32x4 acc[2];
    acc[0] = (f32x4){0.f, 0.f, 0.f, 0.f};
    acc[1] = (f32x4){0.f, 0.f, 0.f, 0.f};

    f16x4 aR0, aR1;
    f16x8 bR0, bR1;
    // prologue: phase 0 -> slot0 -> s[0]; phase 1 -> slot1 (held in regs)
    CLOAD(0, aR0, bR0);
    CLOAD(1, aR1, bR1);
    *(f16x4*)&s_a[0][adst] = aR0;
    *(f16x8*)&s_b[0][bdst] = bR0;
    asm volatile("s_waitcnt lgkmcnt(0)" ::: "memory"); SB();
    __builtin_amdgcn_s_barrier(); SB();

#define CBODY(p, aCur, bCur, aNxt, bNxt, bc, bn) do {                          \
    f16x8 af = *(const f16x8*)&s_a[bc][(wm * 16 + (lane & 15)) * 32 + qa];     \
    f16x8 bf0 = *(const f16x8*)&s_b[bc][(wn * 32 + (lane & 15)) * 32 + qa];    \
    f16x8 bf1 = *(const f16x8*)&s_b[bc][(wn * 32 + 16 + (lane & 15)) * 32 + qa];\
    CLOAD((p) + 2, aCur, bCur);                                                \
    acc[0] = __builtin_amdgcn_mfma_f32_16x16x32_f16(af, bf0, acc[0], 0, 0, 0); \
    acc[1] = __builtin_amdgcn_mfma_f32_16x16x32_f16(af, bf1, acc[1], 0, 0, 0); \
    *(f16x4*)&s_a[bn][adst] = aNxt;                                            \
    *(f16x8*)&s_b[bn][bdst] = bNxt;                                            \
    asm volatile("s_waitcnt lgkmcnt(0)" ::: "memory"); SB();                   \
    __builtin_amdgcn_s_barrier(); SB();                                        \
} while (0)

    for (int p = 0; p < 72; p += 2) {
        CBODY(p,     aR0, bR0, aR1, bR1, 0, 1);
        CBODY(p + 1, aR1, bR1, aR0, bR0, 1, 0);
    }

    // epilogue: wm=0 -> taps 0..7 (rows 4g..4g+3), wm=1 -> tap 8 (rows 16,17)
    const int g = lane >> 4;
#pragma unroll
    for (int ni = 0; ni < 2; ++ni) {
        const int p = p0 + wn * 32 + ni * 16 + (lane & 15);
        const int hwq = p - imgb;
        const int hq = hwq / Wc, wq = hwq - hq * Wc;
        if (wm == 0) {
            store_tap(2 * g,     hq, wq, acc[ni][0] + b_off[4 * g],
                                         acc[ni][1] + b_off[4 * g + 1], p, idx4t, wt4t);
            store_tap(2 * g + 1, hq, wq, acc[ni][2] + b_off[4 * g + 2],
                                         acc[ni][3] + b_off[4 * g + 3], p, idx4t, wt4t);
        } else if (g == 0) {
            store_tap(8, hq, wq, acc[ni][0] + b_off[16],
                                 acc[ni][1] + b_off[17], p, idx4t, wt4t);
        }
    }
#undef CLOAD
#undef CBODY
}

// Fused deformable sampling (f16 NHWC gathers) + f16 MFMA GEMM + ReLU.
// Block: 512 threads (8 waves), tile 256 out x 64 pix; wave = 32x64.
// K=64 chunks (36 total, halved barrier count). 576 blocks, no duplication.
// LDS exactly 80KB (weights ring-2 x 32KB + samples 2 x 8KB) -> 2 blocks/CU
// = 16 waves/CU. Weights 1 chunk ahead; af-read safety via explicit
// vmcnt(4) at chunk top (outstanding there = W(t)x4 + C(t-1)x4 = 8).
__global__ __launch_bounds__(512, 4) void deform_mfma_kernel(
    const f16* __restrict__ x16, const f16* __restrict__ wT2,
    const int4* __restrict__ idx4t, const float4* __restrict__ wt4t,
    f16* __restrict__ o16, float* __restrict__ oN, int last)
{
    __shared__ __align__(16) f16 s_w[2][2][8192];  // [ring][ks][256o x 32c swz] 64KB
    __shared__ __align__(16) f16 s_s[2][2][2048];  // [buf][ks][64p x 32c swz] 16KB

    const int bid = blockIdx.x;
    const int swz = (bid & 7) * 72 + (bid >> 3);   // 576 blocks, XCD-chunked
    const int p0 = swz * 64;
    const int imgb = (p0 / HW) * HW;
    const int tid = threadIdx.x, lane = tid & 63, wid = tid >> 6;
    const int ps = tid >> 3, cg = tid & 7;         // pixel, 8-ch group (of 64)
    const int ksw = cg >> 2, qw = cg & 3;          // write K-half, q within half
    const int qa = ((lane >> 4) ^ ((lane >> 1) & 3)) * 8;
    const int qs = (qw ^ ((ps >> 1) & 3)) * 8;
    const f16* xb = x16 + (size_t)imgb * Cc;

// stage 32KB weights for (tap kt, chunk-quarter cq) -> ring buffer nb
#define ISSUE_W(kt, cq, nb) do {                                               \
    _Pragma("unroll")                                                          \
    for (int h_ = 0; h_ < 2; ++h_) {                                           \
        _Pragma("unroll")                                                      \
        for (int i_ = 0; i_ < 2; ++i_) {                                       \
            int u_ = i_ * 512 + tid;                                           \
            int wr_ = u_ >> 2;                                                 \
            int wc_ = ((u_ & 3) ^ ((u_ >> 3) & 3)) * 8;                        \
            const f16* g_ = wT2 + ((size_t)((kt) * 256 + wr_)) * Cc            \
                          + (cq) * 64 + h_ * 32 + wc_;                         \
            __builtin_amdgcn_global_load_lds(                                  \
                (const __attribute__((address_space(1))) void*)g_,             \
                (__attribute__((address_space(3))) void*)&s_w[nb][h_][u_ * 8], \
                16, 0, 0);                                                     \
        }                                                                      \
    }                                                                          \
} while (0)

// 8 lanes (cg=0..7) of pixel ps read contiguous 128B per corner
#define ISSUE_C(dst, idv, co) do {                                             \
    (dst)[0] = *(const f16x8*)(xb + (size_t)(idv).x * Cc + (co) + cg * 8);     \
    (dst)[1] = *(const f16x8*)(xb + (size_t)(idv).y * Cc + (co) + cg * 8);     \
    (dst)[2] = *(const f16x8*)(xb + (size_t)(idv).z * Cc + (co) + cg * 8);     \
    (dst)[3] = *(const f16x8*)(xb + (size_t)(idv).w * Cc + (co) + cg * 8);     \
} while (0)

#define BLEND_WRITE(src, wvv, nb) do {                                         \
    f16x8 sv_;                                                                 \
    _Pragma("unroll")                                                          \
    for (int j_ = 0; j_ < 8; ++j_) {                                           \
        float s_ = (wvv).x * (float)(src)[0][j_] + (wvv).y * (float)(src)[1][j_]\
                 + (wvv).z * (float)(src)[2][j_] + (wvv).w * (float)(src)[3][j_];\
        sv_[j_] = (f16)s_;                                                     \
    }                                                                          \
    *(f16x8*)&s_s[nb][ksw][ps * 32 + qs] = sv_;                                \
} while (0)

    f32x4 acc[2][4];
#pragma unroll
    for (int mi = 0; mi < 2; ++mi)
#pragma unroll
        for (int ni = 0; ni < 4; ++ni) acc[mi][ni] = (f32x4){0.f, 0.f, 0.f, 0.f};

    f16x8 c4[2][4];
    int4 id = idx4t[p0 + ps];
    float4 wv = wt4t[p0 + ps];
    int4 idN;
    float4 wvN;

    // prologue: W(chunk0)->ring0, W(chunk1)->ring1; C(chunk0)->blend->s_s[0];
    // C(chunk1) left in flight (blended at chunk 0).
    ISSUE_W(0, 0, 0);
    ISSUE_W(0, 1, 1);
    SB();
    ISSUE_C(c4[1], id, 0);                 // corners for chunk 0 (chans 0..63)
    ISSUE_C(c4[0], id, 64);                // corners for chunk 1 (chans 64..127)
    BLEND_WRITE(c4[1], wv, 0);             // vmcnt retires W0,W1,C0 in-order
    asm volatile("s_waitcnt lgkmcnt(0)" ::: "memory"); SB();
    __builtin_amdgcn_s_barrier(); SB();

    for (int k = 0; k < 9; ++k) {
        const int kn = (k < 8) ? k + 1 : 8;
#pragma unroll
        for (int cq = 0; cq < 4; ++cq) {
            const int bb = cq & 1, nb = bb ^ 1;
            // W(this chunk) was issued last chunk; 8 loads outstanding here
            // (W(t)x4 oldest, C(t-1)x4 newest) -> vmcnt(4) retires W(t).
            asm volatile("s_waitcnt vmcnt(4)" ::: "memory"); SB();
            // K-half 0 fragments
            f16x8 af0[2], bf0[4];
#pragma unroll
            for (int mi = 0; mi < 2; ++mi)
                af0[mi] = *(const f16x8*)&s_w[bb][0][(wid * 32 + mi * 16 + (lane & 15)) * 32 + qa];
#pragma unroll
            for (int ni = 0; ni < 4; ++ni)
                bf0[ni] = *(const f16x8*)&s_s[bb][0][(ni * 16 + (lane & 15)) * 32 + qa];
            if (cq == 0) {
                idN = idx4t[(size_t)kn * PIX + p0 + ps];
                wvN = wt4t[(size_t)kn * PIX + p0 + ps];
            }
            // weights for next chunk, then corners for chunk t+2
            ISSUE_W((cq == 3) ? kn : k, (cq + 1) & 3, nb);
            SB();
            {
                const int4 idu = (cq >= 2) ? idN : id;
                ISSUE_C(c4[nb], idu, ((cq + 2) & 3) * 64);
            }
            // blend corners for chunk t+1 (issued at t-1; counted vmcnt)
            {
                const float4 wvu = (cq == 3) ? wvN : wv;
                BLEND_WRITE(c4[bb], wvu, nb);
            }
            asm volatile("s_waitcnt lgkmcnt(0)" ::: "memory"); SB();
#pragma unroll
            for (int ni = 0; ni < 4; ++ni)
#pragma unroll
                for (int mi = 0; mi < 2; ++mi)
                    acc[mi][ni] = __builtin_amdgcn_mfma_f32_16x16x32_f16(
                        af0[mi], bf0[ni], acc[mi][ni], 0, 0, 0);
            // K-half 1 fragments (overlap ks0 MFMAs)
            f16x8 af1[2], bf1[4];
#pragma unroll
            for (int mi = 0; mi < 2; ++mi)
                af1[mi] = *(const f16x8*)&s_w[bb][1][(wid * 32 + mi * 16 + (lane & 15)) * 32 + qa];
#pragma unroll
            for (int ni = 0; ni < 4; ++ni)
                bf1[ni] = *(const f16x8*)&s_s[bb][1][(ni * 16 + (lane & 15)) * 32 + qa];
            asm volatile("s_waitcnt lgkmcnt(0)" ::: "memory"); SB();
#pragma unroll
            for (int ni = 0; ni < 4; ++ni)
#pragma unroll
                for (int mi = 0; mi < 2; ++mi)
                    acc[mi][ni] = __builtin_amdgcn_mfma_f32_16x16x32_f16(
                        af1[mi], bf1[ni], acc[mi][ni], 0, 0, 0);
            __builtin_amdgcn_s_barrier(); SB();
        }
        id = idN;
        wv = wvN;
    }

    // epilogue: ReLU; D row = output = (lane>>4)*4+j, col = pixel = lane&15
    if (!last) {
#pragma unroll
        for (int ni = 0; ni < 4; ++ni) {
            const int p = p0 + ni * 16 + (lane & 15);
#pragma unroll
            for (int mi = 0; mi < 2; ++mi) {
                const int o0 = wid * 32 + mi * 16 + (lane >> 4) * 4;
                f32x4 v = acc[mi][ni];
                f16x4 h = {(f16)fmaxf(v[0], 0.f), (f16)fmaxf(v[1], 0.f),
                           (f16)fmaxf(v[2], 0.f), (f16)fmaxf(v[3], 0.f)};
                *(f16x4*)&o16[(size_t)p * Cc + o0] = h;
            }
        }
    } else {
        const int bimg = imgb / HW;
#pragma unroll
        for (int ni = 0; ni < 4; ++ni) {
            const int p = p0 + ni * 16 + (lane & 15);
            const int hwl = p - imgb;
#pragma unroll
            for (int mi = 0; mi < 2; ++mi) {
                const int o0 = wid * 32 + mi * 16 + (lane >> 4) * 4;
#pragma unroll
                for (int j = 0; j < 4; ++j)
                    oN[((size_t)(bimg * Cc + o0 + j)) * HW + hwl] =
                        fmaxf(acc[mi][ni][j], 0.f);
            }
        }
    }
#undef ISSUE_W
#undef ISSUE_C
#undef BLEND_WRITE
}

extern "C" void kernel_launch(void* const* d_in, const int* in_sizes, int n_in,
                              void* d_out, int out_size, void* d_ws, size_t ws_size,
                              hipStream_t stream)
{
    const float* x0 = (const float*)d_in[0];
    float* out = (float*)d_out;

    f16*   x16a = (f16*)d_ws;                          // PIX*Cc f16
    f16*   x16b = x16a + (size_t)PIX * Cc;             // PIX*Cc f16
    f16*   wT2  = x16b + (size_t)PIX * Cc;             // CK*Cc f16
    f16*   woffT = wT2 + (size_t)CK * Cc;              // 9*32*256 f16
    int4*  idx4t = (int4*)(woffT + (size_t)9 * 32 * Cc);
    float4* wt4t = (float4*)(idx4t + (size_t)KK * PIX);

    nhwc_prep_kernel<<<dim3(HW / 64, Cc / 64, Bc), 256, 0, stream>>>(x0, x16a);

    const f16* xin = x16a;
    for (int L = 0; L < 3; ++L) {
        const float* w_off = (const float*)d_in[1 + 3 * L];
        const float* b_off = (const float*)d_in[2 + 3 * L];
        const float* w     = (const float*)d_in[3 + 3 * L];
        const int last = (L == 2);
        f16* xo = (L == 0) ? x16b : x16a;

        transpose_w_kernel<<<(CK * Cc) / 256, 256, 0, stream>>>(w, wT2);
        woff_prep_kernel<<<(9 * 32 * Cc) / 256, 256, 0, stream>>>(w_off, woffT);
        conv_off_mfma_kernel<<<PIX / 64, 256, 0, stream>>>(xin, woffT, b_off, idx4t, wt4t);
        deform_mfma_kernel<<<PIX / 64, 512, 0, stream>>>(
            xin, wT2, idx4t, wt4t, xo, out, last);

        xin = xo;
    }
}